// Round 1
// baseline (76.825 us; speedup 1.0000x reference)
//
#include <hip/hip_runtime.h>
#include <math.h>

#define NQ 4
#define NL 2

// Precompute cos/sin of weight half-angles (uniform across the batch).
// ws layout: ws[0..7] = cos(w/2) for (l,q) row-major; ws[8..15] = sin(w/2).
__global__ void qweights_kernel(const float* __restrict__ w, float* __restrict__ ws) {
    int i = threadIdx.x;
    if (i < NL * NQ) {
        float h = 0.5f * w[i];
        ws[i]           = __cosf(h);
        ws[NL * NQ + i] = __sinf(h);
    }
}

// One thread = one batch element. State = 16 reals in registers.
// Index convention: k = b0*8 + b1*4 + b2*2 + b3 (wire 0 = MSB), matching the
// reference's [2,2,2,2] flatten and its z-sign table.
__global__ __launch_bounds__(256) void qsim_kernel(
        const float4* __restrict__ x,      // [B] of float4 (x[:,0..3])
        const float* __restrict__ wcs,     // 16 floats: cos then sin
        float4* __restrict__ out,          // [B] of float4 (out[:,0..3])
        int B) {
    int b = blockIdx.x * blockDim.x + threadIdx.x;
    if (b >= B) return;

    float4 xv = x[b];

    // Data encoding RY(x_i) on |0..0>: product state.
    float c0, s0, c1, s1, c2, s2, c3, s3;
    __sincosf(0.5f * xv.x, &s0, &c0);
    __sincosf(0.5f * xv.y, &s1, &c1);
    __sincosf(0.5f * xv.z, &s2, &c2);
    __sincosf(0.5f * xv.w, &s3, &c3);

    float a00 = c0 * c1, a01 = c0 * s1, a10 = s0 * c1, a11 = s0 * s1;  // (b0,b1)
    float g00 = c2 * c3, g01 = c2 * s3, g10 = s2 * c3, g11 = s2 * s3;  // (b2,b3)

    float st[16];
    st[ 0] = a00 * g00; st[ 1] = a00 * g01; st[ 2] = a00 * g10; st[ 3] = a00 * g11;
    st[ 4] = a01 * g00; st[ 5] = a01 * g01; st[ 6] = a01 * g10; st[ 7] = a01 * g11;
    st[ 8] = a10 * g00; st[ 9] = a10 * g01; st[10] = a10 * g10; st[11] = a10 * g11;
    st[12] = a11 * g00; st[13] = a11 * g01; st[14] = a11 * g10; st[15] = a11 * g11;

    // Variational layers: RY(weights[l][q]) on each wire, then CNOT chain.
#pragma unroll
    for (int l = 0; l < NL; ++l) {
#pragma unroll
        for (int q = 0; q < NQ; ++q) {
            float c = wcs[l * NQ + q];
            float s = wcs[NL * NQ + l * NQ + q];
            const int str = 8 >> q;   // stride of wire q's bit
#pragma unroll
            for (int k = 0; k < 16; ++k) {
                if ((k & str) == 0) {
                    float u = st[k], v = st[k + str];
                    st[k]       = c * u - s * v;
                    st[k + str] = s * u + c * v;
                }
            }
        }
        // CNOT(ctrl=q, tgt=q+1): if ctrl bit set, flip target bit.
#pragma unroll
        for (int q = 0; q < NQ - 1; ++q) {
            const int cs = 8 >> q;
            const int ts = 8 >> (q + 1);
#pragma unroll
            for (int k = 0; k < 16; ++k) {
                if ((k & cs) != 0 && (k & ts) == 0) {
                    float t = st[k];
                    st[k] = st[k + ts];
                    st[k + ts] = t;
                }
            }
        }
    }

    // probs + signed sums. p[k] = st[k]^2.
    float p[16];
#pragma unroll
    for (int k = 0; k < 16; ++k) p[k] = st[k] * st[k];

    float q2[8];
    float o3 = 0.f;
#pragma unroll
    for (int i = 0; i < 8; ++i) {
        q2[i] = p[2 * i] + p[2 * i + 1];
        o3   += p[2 * i] - p[2 * i + 1];
    }
    float r4[4];
    float o2 = 0.f;
#pragma unroll
    for (int i = 0; i < 4; ++i) {
        r4[i] = q2[2 * i] + q2[2 * i + 1];
        o2   += q2[2 * i] - q2[2 * i + 1];
    }
    float o1 = (r4[0] - r4[1]) + (r4[2] - r4[3]);
    float o0 = (r4[0] + r4[1]) - (r4[2] + r4[3]);

    out[b] = make_float4(o0, o1, o2, o3);
}

extern "C" void kernel_launch(void* const* d_in, const int* in_sizes, int n_in,
                              void* d_out, int out_size, void* d_ws, size_t ws_size,
                              hipStream_t stream) {
    const float* x = (const float*)d_in[0];        // [B,4]
    const float* w = (const float*)d_in[1];        // [2,4]
    float* out = (float*)d_out;                    // [B,4]
    float* wcs = (float*)d_ws;                     // 16 floats scratch

    int B = in_sizes[0] / 4;

    qweights_kernel<<<1, 64, 0, stream>>>(w, wcs);

    int block = 256;
    int grid = (B + block - 1) / block;
    qsim_kernel<<<grid, block, 0, stream>>>(
        (const float4*)x, wcs, (float4*)out, B);
}

// Round 2
// 76.281 us; speedup vs baseline: 1.0071x; 1.0071x over previous
//
#include <hip/hip_runtime.h>
#include <math.h>

#define NQ 4
#define NL 2

// Single fused kernel: one thread = one batch element; 16-real statevector in
// registers. Weight half-angle cos/sin computed per-thread (wave-uniform,
// ~16 transcendental ops — cheaper than a separate dispatch + d_ws round-trip).
// Index convention: k = b0*8 + b1*4 + b2*2 + b3 (wire 0 = MSB), matching the
// reference's [2,2,2,2] flatten and its z-sign table.
__global__ __launch_bounds__(256) void qsim_kernel(
        const float4* __restrict__ x,      // [B] of float4 (x[:,0..3])
        const float*  __restrict__ w,      // [NL*NQ] weights
        float4* __restrict__ out,          // [B] of float4 (out[:,0..3])
        int B) {
    int b = blockIdx.x * blockDim.x + threadIdx.x;
    if (b >= B) return;

    // Weight trig (uniform across threads; compiler may scalarize).
    float wc[NL * NQ], wsn[NL * NQ];
#pragma unroll
    for (int i = 0; i < NL * NQ; ++i) {
        __sincosf(0.5f * w[i], &wsn[i], &wc[i]);
    }

    float4 xv = x[b];

    // Data encoding RY(x_i) on |0..0>: product state.
    float c0, s0, c1, s1, c2, s2, c3, s3;
    __sincosf(0.5f * xv.x, &s0, &c0);
    __sincosf(0.5f * xv.y, &s1, &c1);
    __sincosf(0.5f * xv.z, &s2, &c2);
    __sincosf(0.5f * xv.w, &s3, &c3);

    float a00 = c0 * c1, a01 = c0 * s1, a10 = s0 * c1, a11 = s0 * s1;  // (b0,b1)
    float g00 = c2 * c3, g01 = c2 * s3, g10 = s2 * c3, g11 = s2 * s3;  // (b2,b3)

    float st[16];
    st[ 0] = a00 * g00; st[ 1] = a00 * g01; st[ 2] = a00 * g10; st[ 3] = a00 * g11;
    st[ 4] = a01 * g00; st[ 5] = a01 * g01; st[ 6] = a01 * g10; st[ 7] = a01 * g11;
    st[ 8] = a10 * g00; st[ 9] = a10 * g01; st[10] = a10 * g10; st[11] = a10 * g11;
    st[12] = a11 * g00; st[13] = a11 * g01; st[14] = a11 * g10; st[15] = a11 * g11;

    // Variational layers: RY(weights[l][q]) on each wire, then CNOT chain.
#pragma unroll
    for (int l = 0; l < NL; ++l) {
#pragma unroll
        for (int q = 0; q < NQ; ++q) {
            float c = wc[l * NQ + q];
            float s = wsn[l * NQ + q];
            const int str = 8 >> q;   // stride of wire q's bit
#pragma unroll
            for (int k = 0; k < 16; ++k) {
                if ((k & str) == 0) {
                    float u = st[k], v = st[k + str];
                    st[k]       = c * u - s * v;
                    st[k + str] = s * u + c * v;
                }
            }
        }
        // CNOT(ctrl=q, tgt=q+1): if ctrl bit set, flip target bit (register
        // permutation — free after unrolling).
#pragma unroll
        for (int q = 0; q < NQ - 1; ++q) {
            const int cs = 8 >> q;
            const int ts = 8 >> (q + 1);
#pragma unroll
            for (int k = 0; k < 16; ++k) {
                if ((k & cs) != 0 && (k & ts) == 0) {
                    float t = st[k];
                    st[k] = st[k + ts];
                    st[k + ts] = t;
                }
            }
        }
    }

    // probs + signed sums. p[k] = st[k]^2.
    float p[16];
#pragma unroll
    for (int k = 0; k < 16; ++k) p[k] = st[k] * st[k];

    float q2[8];
    float o3 = 0.f;
#pragma unroll
    for (int i = 0; i < 8; ++i) {
        q2[i] = p[2 * i] + p[2 * i + 1];
        o3   += p[2 * i] - p[2 * i + 1];
    }
    float r4[4];
    float o2 = 0.f;
#pragma unroll
    for (int i = 0; i < 4; ++i) {
        r4[i] = q2[2 * i] + q2[2 * i + 1];
        o2   += q2[2 * i] - q2[2 * i + 1];
    }
    float o1 = (r4[0] - r4[1]) + (r4[2] - r4[3]);
    float o0 = (r4[0] + r4[1]) - (r4[2] + r4[3]);

    out[b] = make_float4(o0, o1, o2, o3);
}

extern "C" void kernel_launch(void* const* d_in, const int* in_sizes, int n_in,
                              void* d_out, int out_size, void* d_ws, size_t ws_size,
                              hipStream_t stream) {
    const float* x = (const float*)d_in[0];        // [B,4]
    const float* w = (const float*)d_in[1];        // [2,4]
    float* out = (float*)d_out;                    // [B,4]

    int B = in_sizes[0] / 4;

    int block = 256;
    int grid = (B + block - 1) / block;
    qsim_kernel<<<grid, block, 0, stream>>>(
        (const float4*)x, w, (float4*)out, B);
}

// Round 3
// 75.523 us; speedup vs baseline: 1.0172x; 1.0100x over previous
//
#include <hip/hip_runtime.h>
#include <math.h>

#define NQ 4
#define NL 2
#define ELEMS 4   // batch elements per thread: amortizes the 8 weight sincos

// One thread = ELEMS batch elements; 16-real statevector in registers.
// Weight half-angle cos/sin computed once per thread (batch-uniform).
// Index convention: k = b0*8 + b1*4 + b2*2 + b3 (wire 0 = MSB), matching the
// reference's [2,2,2,2] flatten and its z-sign table.
__global__ __launch_bounds__(256) void qsim_kernel(
        const float4* __restrict__ x,      // [B] of float4 (x[:,0..3])
        const float*  __restrict__ w,      // [NL*NQ] weights
        float4* __restrict__ out,          // [B] of float4 (out[:,0..3])
        int B) {
    const int tid   = blockIdx.x * blockDim.x + threadIdx.x;
    const int total = gridDim.x * blockDim.x;   // grid stride

    // Weight trig — once per thread, reused for all ELEMS elements.
    float wc[NL * NQ], wsn[NL * NQ];
#pragma unroll
    for (int i = 0; i < NL * NQ; ++i) {
        __sincosf(0.5f * w[i], &wsn[i], &wc[i]);
    }

#pragma unroll
    for (int e = 0; e < ELEMS; ++e) {
        const int b = tid + e * total;          // coalesced per iteration
        if (b >= B) continue;

        float4 xv = x[b];

        // Data encoding RY(x_i) on |0..0>: product state.
        float c0, s0, c1, s1, c2, s2, c3, s3;
        __sincosf(0.5f * xv.x, &s0, &c0);
        __sincosf(0.5f * xv.y, &s1, &c1);
        __sincosf(0.5f * xv.z, &s2, &c2);
        __sincosf(0.5f * xv.w, &s3, &c3);

        float a00 = c0 * c1, a01 = c0 * s1, a10 = s0 * c1, a11 = s0 * s1;
        float g00 = c2 * c3, g01 = c2 * s3, g10 = s2 * c3, g11 = s2 * s3;

        float st[16];
        st[ 0] = a00 * g00; st[ 1] = a00 * g01; st[ 2] = a00 * g10; st[ 3] = a00 * g11;
        st[ 4] = a01 * g00; st[ 5] = a01 * g01; st[ 6] = a01 * g10; st[ 7] = a01 * g11;
        st[ 8] = a10 * g00; st[ 9] = a10 * g01; st[10] = a10 * g10; st[11] = a10 * g11;
        st[12] = a11 * g00; st[13] = a11 * g01; st[14] = a11 * g10; st[15] = a11 * g11;

        // Variational layers: RY(weights[l][q]) per wire, then CNOT chain.
#pragma unroll
        for (int l = 0; l < NL; ++l) {
#pragma unroll
            for (int q = 0; q < NQ; ++q) {
                float c = wc[l * NQ + q];
                float s = wsn[l * NQ + q];
                const int str = 8 >> q;
#pragma unroll
                for (int k = 0; k < 16; ++k) {
                    if ((k & str) == 0) {
                        float u = st[k], v = st[k + str];
                        st[k]       = c * u - s * v;
                        st[k + str] = s * u + c * v;
                    }
                }
            }
            // CNOT(ctrl=q, tgt=q+1): register permutation — free after unroll.
#pragma unroll
            for (int q = 0; q < NQ - 1; ++q) {
                const int cs = 8 >> q;
                const int ts = 8 >> (q + 1);
#pragma unroll
                for (int k = 0; k < 16; ++k) {
                    if ((k & cs) != 0 && (k & ts) == 0) {
                        float t = st[k];
                        st[k] = st[k + ts];
                        st[k + ts] = t;
                    }
                }
            }
        }

        // probs + signed sums.
        float p[16];
#pragma unroll
        for (int k = 0; k < 16; ++k) p[k] = st[k] * st[k];

        float q2[8];
        float o3 = 0.f;
#pragma unroll
        for (int i = 0; i < 8; ++i) {
            q2[i] = p[2 * i] + p[2 * i + 1];
            o3   += p[2 * i] - p[2 * i + 1];
        }
        float r4[4];
        float o2 = 0.f;
#pragma unroll
        for (int i = 0; i < 4; ++i) {
            r4[i] = q2[2 * i] + q2[2 * i + 1];
            o2   += q2[2 * i] - q2[2 * i + 1];
        }
        float o1 = (r4[0] - r4[1]) + (r4[2] - r4[3]);
        float o0 = (r4[0] + r4[1]) - (r4[2] + r4[3]);

        out[b] = make_float4(o0, o1, o2, o3);
    }
}

extern "C" void kernel_launch(void* const* d_in, const int* in_sizes, int n_in,
                              void* d_out, int out_size, void* d_ws, size_t ws_size,
                              hipStream_t stream) {
    const float* x = (const float*)d_in[0];        // [B,4]
    const float* w = (const float*)d_in[1];        // [2,4]
    float* out = (float*)d_out;                    // [B,4]

    int B = in_sizes[0] / 4;

    int block = 256;
    int grid = (B + block * ELEMS - 1) / (block * ELEMS);
    qsim_kernel<<<grid, block, 0, stream>>>(
        (const float4*)x, w, (float4*)out, B);
}